// Round 11
// baseline (1901.993 us; speedup 1.0000x reference)
//
#include <hip/hip_runtime.h>
#include <math.h>

#define NNODES 10000
#define NEDGES 160000
#define DIM    256
#define BATCH  4
#define NG     8           // BATCH * S streams
#define MROWS  40064       // 40000 padded to 626*64

typedef __attribute__((ext_vector_type(8))) __bf16 bf16x8;
typedef __attribute__((ext_vector_type(4))) float  floatx4;

__device__ __forceinline__ float leakyf(float x){ return x > 0.f ? x : 0.01f*x; }
__device__ __forceinline__ float fsig(float x){ return 1.f/(1.f + __expf(-x)); }
__device__ __forceinline__ float ftanh(float x){ return 1.f - 2.f/(1.f + __expf(2.f*x)); }
__device__ __forceinline__ unsigned short f2bf_u(float x){
  unsigned int u = __float_as_uint(x);
  u += 0x7fffu + ((u >> 16) & 1u);
  return (unsigned short)(u >> 16);
}
__device__ __forceinline__ float bfdec(unsigned short u){
  return __uint_as_float(((unsigned int)u) << 16);
}
#define GATE_SCL 65535.f
#define GATE_INV 1.5259021896696422e-5f

__device__ __forceinline__ void glds16(unsigned short* lds, const unsigned short* g){
  __builtin_amdgcn_global_load_lds(
      (const __attribute__((address_space(1))) void*)g,
      (__attribute__((address_space(3))) void*)lds, 16, 0, 0);
}

// h0: nodes -> ihcat0 h-half (hi) + h_lo
__global__ void ihinit_kernel(const float* __restrict__ nodes,
                              unsigned short* __restrict__ ihcat,
                              unsigned short* __restrict__ h_lo){
  int idx = blockIdx.x*256 + threadIdx.x;   // 40000*256
  int row = idx >> 8, d = idx & 255;
  float v = nodes[idx];
  unsigned short h = f2bf_u(v);
  ihcat[(size_t)row*512 + 256 + d] = h;
  h_lo[idx] = f2bf_u(v - bfdec(h));
}

// ---- weight prep ----
__global__ void w1cat_kernel(const float* __restrict__ ew1, unsigned short* __restrict__ o){
  int idx = blockIdx.x*256 + threadIdx.x;      // 512*256
  int n = idx >> 8, k = idx & 255;
  o[idx] = f2bf_u(ew1[(n>>8)*65536 + (n&255)*256 + k]);
}
__global__ void w2k_kernel(const float* __restrict__ ew2, unsigned short* __restrict__ o){
  int idx = blockIdx.x*256 + threadIdx.x;      // 256*1024
  int n = idx >> 10, kp = idx & 1023;
  int j = kp & 511, term = kp >> 9;
  int si = j >> 8, k = j & 255;
  float v = ew2[si*65536 + n*256 + k];
  unsigned short h = f2bf_u(v);
  o[idx] = term ? f2bf_u(v - bfdec(h)) : h;
}
// wk2[c][kp], kp in [0,512): K' = [hi | lo]
__global__ void wk2_kernel(const float* __restrict__ w, unsigned short* __restrict__ o){
  int idx = blockIdx.x*256 + threadIdx.x;      // 768*512
  int c = idx >> 9, kp = idx & 511;
  int k = kp & 255, term = kp >> 8;
  float v = w[c*256 + k];
  unsigned short h = f2bf_u(v);
  o[idx] = term ? f2bf_u(v - bfdec(h)) : h;
}
// wcomb[c][kp], c in [0,512) (r,z rows), kp: [Wih_hi|Whh_hi|Wih_lo|Whh_lo]
__global__ void wcomb_kernel(const float* __restrict__ wih, const float* __restrict__ whh,
                             unsigned short* __restrict__ o){
  int idx = blockIdx.x*256 + threadIdx.x;      // 512*1024
  int c = idx >> 10, kp = idx & 1023;
  int seg = kp >> 8, k = kp & 255;
  const float* w = (seg & 1) ? whh : wih;
  float v = w[c*256 + k];
  unsigned short h = f2bf_u(v);
  o[idx] = (seg >> 1) ? f2bf_u(v - bfdec(h)) : h;
}

// ---------------- edge sort (counting sort by dst, per stream g) ----------------
__global__ void hist_kernel(const int* __restrict__ edges, int* __restrict__ cnt){
  int idx = blockIdx.x*256 + threadIdx.x;
  if (idx < NG*NEDGES){
    int g = idx / NEDGES, e = idx - g*NEDGES;
    int d = edges[((size_t)g*NEDGES + e)*2];
    atomicAdd(&cnt[g*NNODES + d], 1);
  }
}

__global__ __launch_bounds__(256) void scan_kernel(const int* __restrict__ cnt, int* __restrict__ off){
  __shared__ int sc[256];
  int g = blockIdx.x, t = threadIdx.x;
  int base = 0;
  for (int c=0;c<40;c++){
    int i = c*256 + t;
    int v = (i < NNODES) ? cnt[g*NNODES + i] : 0;
    __syncthreads();
    sc[t] = v;
    __syncthreads();
    for (int o=1;o<256;o<<=1){
      int u = (t>=o) ? sc[t-o] : 0;
      __syncthreads();
      sc[t] += u;
      __syncthreads();
    }
    if (i < NNODES) off[g*(NNODES+1) + i] = base + sc[t] - v;
    base += sc[255];
  }
  if (t == 0) off[g*(NNODES+1) + NNODES] = base;
}

__global__ void scatter_kernel(const int* __restrict__ edges, const int* __restrict__ off,
                               int* __restrict__ cur, int* __restrict__ ssrc){
  int idx = blockIdx.x*256 + threadIdx.x;
  if (idx < NG*NEDGES){
    int g = idx / NEDGES, e = idx - g*NEDGES;
    const int* ep = &edges[((size_t)g*NEDGES + e)*2];
    int d = ep[0], s = ep[1];
    int pos = off[g*(NNODES+1) + d] + atomicAdd(&cur[g*NNODES + d], 1);
    ssrc[g*NEDGES + pos] = s;
  }
}

// ================= 64x128 double-buffered LDS-staged MFMA core =================
// lds layout: buf b at lds + b*12288 : A(64*64) then B(128*64).
// Prefetch chunk k+1 into alt buffer BEFORE computing chunk k; the barrier after
// compute drains the prefetch (overlapping its latency with the MFMA phase).
template<int KP, int RS, int KM>
__device__ __forceinline__ void mm64_core(
    const unsigned short* __restrict__ Ab, const unsigned short* __restrict__ Wb,
    unsigned short* lds, floatx4 (&acc)[4][2])
{
  const int t = threadIdx.x;
  const int w = t >> 6, lane = t & 63;
  const int q = lane >> 4, col = lane & 15;
  const int wc = w*32;
  const int sr = t >> 3;
  const int sj = t & 7;
  const int sk = ((sj ^ (sr & 7)) * 8);

  // prologue: chunk 0 -> buf 0
  {
    unsigned short* Al = lds;
    unsigned short* Bl = lds + 4096;
    #pragma unroll
    for (int i=0;i<2;i++){
      int r = i*32 + sr;
      glds16(&Al[i*2048 + w*512], &Ab[(size_t)r*RS + (sk & KM)]);
    }
    #pragma unroll
    for (int i=0;i<4;i++){
      int r = i*32 + sr;
      glds16(&Bl[i*2048 + w*512], &Wb[(size_t)r*KP + sk]);
    }
  }
  __syncthreads();

  int cur = 0;
  for (int kb = 0; kb < KP; kb += 64){
    int nkb = kb + 64;
    if (nkb < KP){
      unsigned short* Al = lds + (cur^1)*12288;
      unsigned short* Bl = Al + 4096;
      #pragma unroll
      for (int i=0;i<2;i++){
        int r = i*32 + sr;
        glds16(&Al[i*2048 + w*512], &Ab[(size_t)r*RS + ((nkb + sk) & KM)]);
      }
      #pragma unroll
      for (int i=0;i<4;i++){
        int r = i*32 + sr;
        glds16(&Bl[i*2048 + w*512], &Wb[(size_t)r*KP + nkb + sk]);
      }
    }
    unsigned short* Al = lds + cur*12288;
    unsigned short* Bl = Al + 4096;
    #pragma unroll
    for (int ks2=0; ks2<2; ks2++){
      bf16x8 a[4], bf[2];
      #pragma unroll
      for (int mi=0;mi<4;mi++){
        int r = mi*16 + col;
        int j = (ks2*4 + q) ^ (r & 7);
        a[mi] = *(const bf16x8*)&Al[r*64 + j*8];
      }
      #pragma unroll
      for (int ni=0;ni<2;ni++){
        int r = wc + ni*16 + col;
        int j = (ks2*4 + q) ^ (r & 7);
        bf[ni] = *(const bf16x8*)&Bl[r*64 + j*8];
      }
      #pragma unroll
      for (int mi=0;mi<4;mi++)
        #pragma unroll
        for (int ni=0;ni<2;ni++)
          acc[mi][ni] = __builtin_amdgcn_mfma_f32_16x16x32_bf16(a[mi], bf[ni], acc[mi][ni], 0,0,0);
    }
    __syncthreads();
    cur ^= 1;
  }
}

#define MMPRO \
  const int t = threadIdx.x, w = t >> 6, lane = t & 63; \
  const int q = lane >> 4, col = lane & 15; \
  const int wc = w*32; \
  floatx4 acc[4][2]; \
  _Pragma("unroll") for (int mi=0;mi<4;mi++) _Pragma("unroll") for (int ni=0;ni<2;ni++) \
    acc[mi][ni] = (floatx4){0.f,0.f,0.f,0.f};

// ---- Z = leaky(h @ W1cat^T + b1): grid (626, 4); h read from ihcat h-half ----
__global__ __launch_bounds__(256) void z64_kernel(
    const unsigned short* __restrict__ ihcat, const unsigned short* __restrict__ w1cat,
    const float* __restrict__ eb1, unsigned short* __restrict__ Z)
{
  __shared__ unsigned short lds[24576];
  const int row0 = blockIdx.x*64, col0 = blockIdx.y*128;
  MMPRO
  mm64_core<256,512,255>(ihcat + (size_t)row0*512 + 256, w1cat + (size_t)col0*256, lds, acc);

  #pragma unroll
  for (int ni=0;ni<2;ni++){
    int n = col0 + wc + ni*16 + col;
    int si = n >> 8, cz = n & 255;
    float bb = eb1[si*256 + cz];
    unsigned short* zp = Z + (size_t)si*MROWS*256 + cz;
    #pragma unroll
    for (int mi=0;mi<4;mi++)
      #pragma unroll
      for (int rr=0;rr<4;rr++){
        int row = row0 + mi*16 + q*4 + rr;
        zp[(size_t)row*256] = f2bf_u(leakyf(acc[mi][ni][rr] + bb));
      }
  }
}

// ---- CSR aggregate, XCD-pinned: g = bid & 7; 4 nodes per wave ----
__global__ __launch_bounds__(256) void aggregate_kernel(
    const unsigned short* __restrict__ Z, const int* __restrict__ ssrc,
    const int* __restrict__ off, unsigned short* __restrict__ Sb)
{
  const int bid = blockIdx.x;          // 5000
  const int g = bid & 7;
  const int dgrp = bid >> 3;           // 0..624
  const int b = g >> 1, si = g & 1;
  const int w = threadIdx.x >> 6, lane = threadIdx.x & 63;
  const unsigned short* zb = Z + ((size_t)si*MROWS + b*10000)*256 + lane*4;
  const int* sp = ssrc + (size_t)g*NEDGES;
  const int* offg = off + g*(NNODES+1);

  #pragma unroll
  for (int i=0;i<4;i++){
    const int d = dgrp*16 + w*4 + i;
    const int j0 = offg[d], j1 = offg[d+1];
    float a0=0.f, a1=0.f, a2=0.f, a3=0.f;
    int j = j0;
    for (; j+4 <= j1; j+=4){
      int s0=sp[j], s1=sp[j+1], s2=sp[j+2], s3=sp[j+3];
      ushort4 u0 = *(const ushort4*)&zb[(size_t)s0*256];
      ushort4 u1 = *(const ushort4*)&zb[(size_t)s1*256];
      ushort4 u2 = *(const ushort4*)&zb[(size_t)s2*256];
      ushort4 u3 = *(const ushort4*)&zb[(size_t)s3*256];
      a0 += bfdec(u0.x)+bfdec(u1.x)+bfdec(u2.x)+bfdec(u3.x);
      a1 += bfdec(u0.y)+bfdec(u1.y)+bfdec(u2.y)+bfdec(u3.y);
      a2 += bfdec(u0.z)+bfdec(u1.z)+bfdec(u2.z)+bfdec(u3.z);
      a3 += bfdec(u0.w)+bfdec(u1.w)+bfdec(u2.w)+bfdec(u3.w);
    }
    for (; j < j1; j++){
      ushort4 u = *(const ushort4*)&zb[(size_t)sp[j]*256];
      a0 += bfdec(u.x); a1 += bfdec(u.y); a2 += bfdec(u.z); a3 += bfdec(u.w);
    }
    size_t so = (size_t)(b*10000 + d)*512 + si*256 + lane*4;
    ushort4 h;
    h.x = f2bf_u(a0); h.y = f2bf_u(a1); h.z = f2bf_u(a2); h.w = f2bf_u(a3);
    *(ushort4*)&Sb[so] = h;
  }
}

// ---- ihcat.ib = S @ W2k^T (2-term K'=1024) + deg.b2: grid (626, 2) ----
__global__ __launch_bounds__(256) void w264_kernel(
    const unsigned short* __restrict__ Sb, const unsigned short* __restrict__ w2k,
    const float* __restrict__ eb2, const int* __restrict__ off,
    unsigned short* __restrict__ ihcat)
{
  __shared__ unsigned short lds[24576];
  const int row0 = blockIdx.x*64, col0 = blockIdx.y*128;
  MMPRO
  mm64_core<1024,512,511>(Sb + (size_t)row0*512, w2k + (size_t)col0*1024, lds, acc);

  float b20[2], b21[2];
  #pragma unroll
  for (int ni=0;ni<2;ni++){
    int n = col0 + wc + ni*16 + col;
    b20[ni] = eb2[n];
    b21[ni] = eb2[256 + n];
  }
  #pragma unroll
  for (int mi=0;mi<4;mi++)
    #pragma unroll
    for (int rr=0;rr<4;rr++){
      int row = row0 + mi*16 + q*4 + rr;
      int b = row / 10000, d = row - b*10000;
      float dg0 = 0.f, dg1 = 0.f;
      if (row < 40000){
        int o0 = (b*2)*(NNODES+1) + d;
        int o1 = (b*2+1)*(NNODES+1) + d;
        dg0 = (float)(off[o0+1] - off[o0]);
        dg1 = (float)(off[o1+1] - off[o1]);
      }
      #pragma unroll
      for (int ni=0;ni<2;ni++){
        int n = col0 + wc + ni*16 + col;
        ihcat[(size_t)row*512 + n] = f2bf_u(acc[mi][ni][rr] + dg0*b20[ni] + dg1*b21[ni]);
      }
    }
}

// ---- gruA: combined r,z GEMM -> u16 gates. grid (626,4) ----
__global__ __launch_bounds__(256) void gruA_kernel(
    const unsigned short* __restrict__ ihcat, const unsigned short* __restrict__ wcomb,
    const float* __restrict__ b_ih, const float* __restrict__ b_hh,
    unsigned short* __restrict__ rz_r, unsigned short* __restrict__ rz_z)
{
  __shared__ unsigned short lds[24576];
  const int row0 = blockIdx.x*64, col0 = blockIdx.y*128;
  MMPRO
  mm64_core<1024,512,511>(ihcat + (size_t)row0*512, wcomb + (size_t)col0*1024, lds, acc);

  float bb[2];
  #pragma unroll
  for (int ni=0;ni<2;ni++){
    int n = col0 + wc + ni*16 + col;
    bb[ni] = b_ih[n] + b_hh[n];
  }
  unsigned short* dst = (col0 < 256) ? rz_r : rz_z;
  const int cbase = (col0 & 255) + wc;
  #pragma unroll
  for (int mi=0;mi<4;mi++)
    #pragma unroll
    for (int rr=0;rr<4;rr++){
      size_t row = (size_t)(row0 + mi*16 + q*4 + rr);
      #pragma unroll
      for (int ni=0;ni<2;ni++){
        float v = fsig(acc[mi][ni][rr] + bb[ni]);
        dst[row*256 + cbase + ni*16 + col] = (unsigned short)(v*GATE_SCL + 0.5f);
      }
    }
}

// ---- gruB: n gate + GRU update. grid (626,2). Writes ihcat_nxt h-half + h_lo ----
__global__ __launch_bounds__(256) void gruB_kernel(
    const unsigned short* __restrict__ ihcat, unsigned short* __restrict__ h_lo,
    const unsigned short* __restrict__ wihk, const unsigned short* __restrict__ whhk,
    const float* __restrict__ b_ih, const float* __restrict__ b_hh,
    const unsigned short* __restrict__ rz_r, const unsigned short* __restrict__ rz_z,
    unsigned short* __restrict__ ihcat_nxt)
{
  __shared__ unsigned short lds[24576];
  const int row0 = blockIdx.x*64, dcol0 = blockIdx.y*128;   // n-gate W cols = 512 + dcol0
  const int t = threadIdx.x, w = t >> 6, lane = t & 63;
  const int q = lane >> 4, col = lane & 15;
  const int wc = w*32;

  floatx4 ai[4][2], ah[4][2];
  #pragma unroll
  for (int mi=0;mi<4;mi++)
    #pragma unroll
    for (int ni=0;ni<2;ni++){ ai[mi][ni] = (floatx4){0.f,0.f,0.f,0.f}; ah[mi][ni] = (floatx4){0.f,0.f,0.f,0.f}; }

  mm64_core<512,512,255>(ihcat + (size_t)row0*512,       wihk + (size_t)(512 + dcol0)*512, lds, ai);
  mm64_core<512,512,255>(ihcat + (size_t)row0*512 + 256, whhk + (size_t)(512 + dcol0)*512, lds, ah);

  float bi[2], bh[2];
  #pragma unroll
  for (int ni=0;ni<2;ni++){
    int n = 512 + dcol0 + wc + ni*16 + col;
    bi[ni] = b_ih[n]; bh[ni] = b_hh[n];
  }
  #pragma unroll
  for (int mi=0;mi<4;mi++)
    #pragma unroll
    for (int rr=0;rr<4;rr++){
      size_t row = (size_t)(row0 + mi*16 + q*4 + rr);
      #pragma unroll
      for (int ni=0;ni<2;ni++){
        int dn = dcol0 + wc + ni*16 + col;
        float rg = (float)rz_r[row*256 + dn] * GATE_INV;
        float zg = (float)rz_z[row*256 + dn] * GATE_INV;
        float ng = ftanh(ai[mi][ni][rr] + bi[ni] + rg*(ah[mi][ni][rr] + bh[ni]));
        float hv = bfdec(ihcat[row*512 + 256 + dn]) + bfdec(h_lo[row*256 + dn]);
        float hnew = (1.f - zg)*ng + zg*hv;
        unsigned short hh = f2bf_u(hnew);
        ihcat_nxt[row*512 + 256 + dn] = hh;
        h_lo[row*256 + dn] = f2bf_u(hnew - bfdec(hh));
      }
    }
}

__global__ void reduce_kernel(const unsigned short* __restrict__ ihcat,
                              const unsigned short* __restrict__ h_lo,
                              float* __restrict__ sbuf){
  int b  = blockIdx.x / 50;
  int s0 = (blockIdx.x % 50) * 200;
  int d  = threadIdx.x;
  size_t row = (size_t)b*NNODES + s0;
  float acc = 0.f;
  for (int i=0;i<200;i++){
    acc += bfdec(ihcat[(row+i)*512 + 256 + d]) + bfdec(h_lo[(row+i)*256 + d]);
  }
  atomicAdd(&sbuf[b*DIM + d], acc);
}

__global__ __launch_bounds__(320) void head_kernel(
    const float* __restrict__ sbuf, const float* __restrict__ pt,
    const float* __restrict__ fc1w, const float* __restrict__ fc1b,
    const float* __restrict__ fc2w, const float* __restrict__ fc2b,
    const float* __restrict__ fc3w, const float* __restrict__ fc3b,
    float* __restrict__ out)
{
  __shared__ float L[4][257];
  __shared__ float T1[4][80];
  __shared__ float T2[4][80];
  __shared__ float fmx[4];
  int t = threadIdx.x;
  if (t < 256){
    for (int b=0;b<4;b++){
      float v = sbuf[b*DIM + t];
      float ll = logf(v);
      if (ll != ll) ll = 0.f;
      ll = fmaxf(ll, 0.f);
      L[b][t] = ll;
    }
  }
  __syncthreads();
  int w = t >> 6, lane = t & 63;
  if (w < 4){
    float m = -INFINITY;
    for (int i=lane;i<256;i+=64){ float v = L[w][i]; if (v != INFINITY) m = fmaxf(m, v); }
    #pragma unroll
    for (int o=32;o>=1;o>>=1) m = fmaxf(m, __shfl_xor(m, o, 64));
    if (lane==0) fmx[w] = m;
  }
  __syncthreads();
  if (t < 256){
    for (int b=0;b<4;b++) if (L[b][t] == INFINITY) L[b][t] = fmx[b];
  }
  if (t < 4) L[t][256] = pt[t];
  __syncthreads();
  if (t < 320){
    int b = t/80, i = t%80;
    float a = fc1b[i];
    for (int k=0;k<257;k++) a += L[b][k]*fc1w[i*257+k];
    T1[b][i] = leakyf(a);
  }
  __syncthreads();
  if (t < 320){
    int b = t/80, i = t%80;
    float a = fc2b[i];
    for (int k=0;k<80;k++) a += T1[b][k]*fc2w[i*80+k];
    T2[b][i] = leakyf(a);
  }
  __syncthreads();
  if (t < 40){
    int b = t/10, i = t%10;
    float a = fc3b[i];
    for (int k=0;k<80;k++) a += T2[b][k]*fc3w[i*80+k];
    out[b*10+i] = a;
  }
}

extern "C" void kernel_launch(void* const* d_in, const int* in_sizes, int n_in,
                              void* d_out, int out_size, void* d_ws, size_t ws_size,
                              hipStream_t stream) {
  const float* nodes = (const float*)d_in[0];
  const int*   edges = (const int*)d_in[1];
  const float* pt    = (const float*)d_in[2];
  const float* w_ih  = (const float*)d_in[3];
  const float* w_hh  = (const float*)d_in[4];
  const float* b_ih  = (const float*)d_in[5];
  const float* b_hh  = (const float*)d_in[6];
  const float* ew1   = (const float*)d_in[7];
  const float* eb1   = (const float*)d_in[8];
  const float* ew2   = (const float*)d_in[9];
  const float* eb2   = (const float*)d_in[10];
  const float* fc1w  = (const float*)d_in[11];
  const float* fc1b  = (const float*)d_in[12];
  const float* fc2w  = (const float*)d_in[13];
  const float* fc2b  = (const float*)d_in[14];
  const float* fc3w  = (const float*)d_in[15];
  const float* fc3b  = (const float*)d_in[16];

  const size_t HN  = (size_t)BATCH*NNODES*DIM;    // 10,240,000 (real rows)
  const size_t HNP = (size_t)MROWS*DIM;
  char* p = (char*)d_ws;
  float* sbuf = (float*)p;                        p += BATCH*DIM*4;
  unsigned short* ihcat0 = (unsigned short*)p;    p += (size_t)MROWS*512*2;  // [ib | h]
  unsigned short* ihcat1 = (unsigned short*)p;    p += (size_t)MROWS*512*2;
  unsigned short* h_lo   = (unsigned short*)p;    p += HNP*2;
  unsigned short* Zb   = (unsigned short*)p;      p += 2*HNP*2;              // z/agg scratch
  unsigned short* Sb   = (unsigned short*)p;      p += (size_t)MROWS*512*2;  // dead after w2 -> rz
  unsigned short* w1cat= (unsigned short*)p;      p += 512*256*2;
  unsigned short* w2k  = (unsigned short*)p;      p += 256*1024*2;
  unsigned short* wihk = (unsigned short*)p;      p += 768*512*2;
  unsigned short* whhk = (unsigned short*)p;      p += 768*512*2;
  unsigned short* wcomb= (unsigned short*)p;      p += 512*1024*2;
  int* off  = (int*)p;                            p += NG*(NNODES+1)*4;
  int* cur  = (int*)p;                            p += NG*NNODES*4;
  int* ssrc = (int*)p;                            p += (size_t)NG*NEDGES*4;

  unsigned short* rz_r = (unsigned short*)Sb;              // MROWS*256 u16
  unsigned short* rz_z = rz_r + (size_t)MROWS*256;         // MROWS*256 u16

  // weights
  w1cat_kernel<<<512,256,0,stream>>>(ew1, w1cat);
  w2k_kernel<<<1024,256,0,stream>>>(ew2, w2k);
  wk2_kernel<<<1536,256,0,stream>>>(w_ih, wihk);
  wk2_kernel<<<1536,256,0,stream>>>(w_hh, whhk);
  wcomb_kernel<<<2048,256,0,stream>>>(w_ih, w_hh, wcomb);

  // h0
  ihinit_kernel<<<(int)(HN/256),256,0,stream>>>(nodes, ihcat0, h_lo);

  // counting sort (CSR) of edges by dst, per stream g
  hipMemsetAsync(cur, 0, NG*NNODES*sizeof(int), stream);
  hist_kernel<<<(NG*NEDGES)/256,256,0,stream>>>(edges, cur);
  scan_kernel<<<NG,256,0,stream>>>(cur, off);
  hipMemsetAsync(cur, 0, NG*NNODES*sizeof(int), stream);
  scatter_kernel<<<(NG*NEDGES)/256,256,0,stream>>>(edges, off, cur, ssrc);

  hipMemsetAsync(sbuf, 0, BATCH*DIM*sizeof(float), stream);

  unsigned short* ih[2] = {ihcat0, ihcat1};

  for (int pass=0; pass<6; pass++){
    unsigned short* curb = ih[pass & 1];
    unsigned short* nxtb = ih[(pass+1) & 1];
    z64_kernel<<<dim3(MROWS/64,4),256,0,stream>>>(curb, w1cat, eb1, Zb);
    aggregate_kernel<<<5000,256,0,stream>>>(Zb, ssrc, off, Sb);
    w264_kernel<<<dim3(MROWS/64,2),256,0,stream>>>(Sb, w2k, eb2, off, curb);
    gruA_kernel<<<dim3(MROWS/64,4),256,0,stream>>>(curb, wcomb, b_ih, b_hh, rz_r, rz_z);
    gruB_kernel<<<dim3(MROWS/64,2),256,0,stream>>>(curb, h_lo, wihk, whhk, b_ih, b_hh,
                                                   rz_r, rz_z, nxtb);
  }
  reduce_kernel<<<200,256,0,stream>>>(ih[0], h_lo, sbuf);
  head_kernel<<<1,320,0,stream>>>(sbuf, pt, fc1w,fc1b,fc2w,fc2b,fc3w,fc3b,(float*)d_out);
}

// Round 12
// 1689.330 us; speedup vs baseline: 1.1259x; 1.1259x over previous
//
#include <hip/hip_runtime.h>
#include <math.h>

#define NNODES 10000
#define NEDGES 160000
#define DIM    256
#define BATCH  4
#define NG     8           // BATCH * S streams
#define MROWS  40064       // buffer row stride (40000 real rows; 625 row-blocks of 64)
#define RBLK   625         // real row-blocks
#define RGRP   79          // ceil(625/8) groups -> 632 grid slots per col

typedef __attribute__((ext_vector_type(8))) __bf16 bf16x8;
typedef __attribute__((ext_vector_type(4))) float  floatx4;

__device__ __forceinline__ float leakyf(float x){ return x > 0.f ? x : 0.01f*x; }
__device__ __forceinline__ float fsig(float x){ return 1.f/(1.f + __expf(-x)); }
__device__ __forceinline__ float ftanh(float x){ return 1.f - 2.f/(1.f + __expf(2.f*x)); }
__device__ __forceinline__ unsigned short f2bf_u(float x){
  unsigned int u = __float_as_uint(x);
  u += 0x7fffu + ((u >> 16) & 1u);
  return (unsigned short)(u >> 16);
}
__device__ __forceinline__ float bfdec(unsigned short u){
  return __uint_as_float(((unsigned int)u) << 16);
}
#define GATE_SCL 65535.f
#define GATE_INV 1.5259021896696422e-5f

__device__ __forceinline__ void glds16(unsigned short* lds, const unsigned short* g){
  __builtin_amdgcn_global_load_lds(
      (const __attribute__((address_space(1))) void*)g,
      (__attribute__((address_space(3))) void*)lds, 16, 0, 0);
}

// h0: nodes -> ihcat0 h-half (hi) + h_lo
__global__ void ihinit_kernel(const float* __restrict__ nodes,
                              unsigned short* __restrict__ ihcat,
                              unsigned short* __restrict__ h_lo){
  int idx = blockIdx.x*256 + threadIdx.x;   // 40000*256
  int row = idx >> 8, d = idx & 255;
  float v = nodes[idx];
  unsigned short h = f2bf_u(v);
  ihcat[(size_t)row*512 + 256 + d] = h;
  h_lo[idx] = f2bf_u(v - bfdec(h));
}

// ---- weight prep ----
__global__ void w1cat_kernel(const float* __restrict__ ew1, unsigned short* __restrict__ o){
  int idx = blockIdx.x*256 + threadIdx.x;      // 512*256
  int n = idx >> 8, k = idx & 255;
  o[idx] = f2bf_u(ew1[(n>>8)*65536 + (n&255)*256 + k]);
}
__global__ void w2k_kernel(const float* __restrict__ ew2, unsigned short* __restrict__ o){
  int idx = blockIdx.x*256 + threadIdx.x;      // 256*1024
  int n = idx >> 10, kp = idx & 1023;
  int j = kp & 511, term = kp >> 9;
  int si = j >> 8, k = j & 255;
  float v = ew2[si*65536 + n*256 + k];
  unsigned short h = f2bf_u(v);
  o[idx] = term ? f2bf_u(v - bfdec(h)) : h;
}
// wk2[c][kp], kp in [0,512): K' = [hi | lo]
__global__ void wk2_kernel(const float* __restrict__ w, unsigned short* __restrict__ o){
  int idx = blockIdx.x*256 + threadIdx.x;      // 768*512
  int c = idx >> 9, kp = idx & 511;
  int k = kp & 255, term = kp >> 8;
  float v = w[c*256 + k];
  unsigned short h = f2bf_u(v);
  o[idx] = term ? f2bf_u(v - bfdec(h)) : h;
}
// wcomb[c][kp], c in [0,512) (r,z rows), kp: [Wih_hi|Whh_hi|Wih_lo|Whh_lo]
__global__ void wcomb_kernel(const float* __restrict__ wih, const float* __restrict__ whh,
                             unsigned short* __restrict__ o){
  int idx = blockIdx.x*256 + threadIdx.x;      // 512*1024
  int c = idx >> 10, kp = idx & 1023;
  int seg = kp >> 8, k = kp & 255;
  const float* w = (seg & 1) ? whh : wih;
  float v = w[c*256 + k];
  unsigned short h = f2bf_u(v);
  o[idx] = (seg >> 1) ? f2bf_u(v - bfdec(h)) : h;
}

// ---------------- edge sort (counting sort by dst, per stream g) ----------------
__global__ void hist_kernel(const int* __restrict__ edges, int* __restrict__ cnt){
  int idx = blockIdx.x*256 + threadIdx.x;
  if (idx < NG*NEDGES){
    int g = idx / NEDGES, e = idx - g*NEDGES;
    int d = edges[((size_t)g*NEDGES + e)*2];
    atomicAdd(&cnt[g*NNODES + d], 1);
  }
}

__global__ __launch_bounds__(256) void scan_kernel(const int* __restrict__ cnt, int* __restrict__ off){
  __shared__ int sc[256];
  int g = blockIdx.x, t = threadIdx.x;
  int base = 0;
  for (int c=0;c<40;c++){
    int i = c*256 + t;
    int v = (i < NNODES) ? cnt[g*NNODES + i] : 0;
    __syncthreads();
    sc[t] = v;
    __syncthreads();
    for (int o=1;o<256;o<<=1){
      int u = (t>=o) ? sc[t-o] : 0;
      __syncthreads();
      sc[t] += u;
      __syncthreads();
    }
    if (i < NNODES) off[g*(NNODES+1) + i] = base + sc[t] - v;
    base += sc[255];
  }
  if (t == 0) off[g*(NNODES+1) + NNODES] = base;
}

__global__ void scatter_kernel(const int* __restrict__ edges, const int* __restrict__ off,
                               int* __restrict__ cur, int* __restrict__ ssrc){
  int idx = blockIdx.x*256 + threadIdx.x;
  if (idx < NG*NEDGES){
    int g = idx / NEDGES, e = idx - g*NEDGES;
    const int* ep = &edges[((size_t)g*NEDGES + e)*2];
    int d = ep[0], s = ep[1];
    int pos = off[g*(NNODES+1) + d] + atomicAdd(&cur[g*NNODES + d], 1);
    ssrc[g*NEDGES + pos] = s;
  }
}

// ================= 64x128 single-buffer LDS-staged MFMA core (R10) =================
template<int KP, int RS, int KM>
__device__ __forceinline__ void mm64_core(
    const unsigned short* __restrict__ Ab, const unsigned short* __restrict__ Wb,
    unsigned short* lds, floatx4 (&acc)[4][2])
{
  const int t = threadIdx.x;
  const int w = t >> 6, lane = t & 63;
  const int q = lane >> 4, col = lane & 15;
  const int wc = w*32;
  unsigned short* Al = lds;           // 64*64
  unsigned short* Bl = lds + 64*64;   // 128*64

  const int sr = t >> 3;
  const int sj = t & 7;
  const int sk = ((sj ^ (sr & 7)) * 8);

  for (int kb = 0; kb < KP; kb += 64){
    #pragma unroll
    for (int i=0;i<2;i++){
      int r = i*32 + sr;
      glds16(&Al[i*2048 + w*512], &Ab[(size_t)r*RS + ((kb + sk) & KM)]);
    }
    #pragma unroll
    for (int i=0;i<4;i++){
      int r = i*32 + sr;
      glds16(&Bl[i*2048 + w*512], &Wb[(size_t)r*KP + kb + sk]);
    }
    __syncthreads();
    #pragma unroll
    for (int ks2=0; ks2<2; ks2++){
      bf16x8 a[4], bf[2];
      #pragma unroll
      for (int mi=0;mi<4;mi++){
        int r = mi*16 + col;
        int j = (ks2*4 + q) ^ (r & 7);
        a[mi] = *(const bf16x8*)&Al[r*64 + j*8];
      }
      #pragma unroll
      for (int ni=0;ni<2;ni++){
        int r = wc + ni*16 + col;
        int j = (ks2*4 + q) ^ (r & 7);
        bf[ni] = *(const bf16x8*)&Bl[r*64 + j*8];
      }
      #pragma unroll
      for (int mi=0;mi<4;mi++)
        #pragma unroll
        for (int ni=0;ni<2;ni++)
          acc[mi][ni] = __builtin_amdgcn_mfma_f32_16x16x32_bf16(a[mi], bf[ni], acc[mi][ni], 0,0,0);
    }
    __syncthreads();
  }
}

// XCD-aligned 1-D grid decode: row-block rb lands on XCD rb%8 (bid%8 == rb%8).
// Grid size = RGRP*8*NCOL; slots with rb >= RBLK exit.
#define XDECODE(NCOL) \
  const int bid_ = blockIdx.x; \
  const int rb_ = ((bid_ >> 3) / NCOL) * 8 + (bid_ & 7); \
  const int colb_ = (bid_ >> 3) % NCOL; \
  if (rb_ >= RBLK) return;

#define MMPRO \
  const int t = threadIdx.x, w = t >> 6, lane = t & 63; \
  const int q = lane >> 4, col = lane & 15; \
  const int wc = w*32; \
  floatx4 acc[4][2]; \
  _Pragma("unroll") for (int mi=0;mi<4;mi++) _Pragma("unroll") for (int ni=0;ni<2;ni++) \
    acc[mi][ni] = (floatx4){0.f,0.f,0.f,0.f};

// ---- Z = leaky(h @ W1cat^T + b1): NCOL=4; h read from ihcat h-half ----
__global__ __launch_bounds__(256) void z64_kernel(
    const unsigned short* __restrict__ ihcat, const unsigned short* __restrict__ w1cat,
    const float* __restrict__ eb1, unsigned short* __restrict__ Z)
{
  __shared__ unsigned short lds[12288];
  XDECODE(4)
  const int row0 = rb_*64, col0 = colb_*128;
  MMPRO
  mm64_core<256,512,255>(ihcat + (size_t)row0*512 + 256, w1cat + (size_t)col0*256, lds, acc);

  #pragma unroll
  for (int ni=0;ni<2;ni++){
    int n = col0 + wc + ni*16 + col;
    int si = n >> 8, cz = n & 255;
    float bb = eb1[si*256 + cz];
    unsigned short* zp = Z + (size_t)si*MROWS*256 + cz;
    #pragma unroll
    for (int mi=0;mi<4;mi++)
      #pragma unroll
      for (int rr=0;rr<4;rr++){
        int row = row0 + mi*16 + q*4 + rr;
        zp[(size_t)row*256] = f2bf_u(leakyf(acc[mi][ni][rr] + bb));
      }
  }
}

// ---- CSR aggregate, XCD-pinned to stream: g = bid & 7; 4 nodes per wave ----
__global__ __launch_bounds__(256) void aggregate_kernel(
    const unsigned short* __restrict__ Z, const int* __restrict__ ssrc,
    const int* __restrict__ off, unsigned short* __restrict__ Sb)
{
  const int bid = blockIdx.x;          // 5000
  const int g = bid & 7;
  const int dgrp = bid >> 3;           // 0..624
  const int b = g >> 1, si = g & 1;
  const int w = threadIdx.x >> 6, lane = threadIdx.x & 63;
  const unsigned short* zb = Z + ((size_t)si*MROWS + b*10000)*256 + lane*4;
  const int* sp = ssrc + (size_t)g*NEDGES;
  const int* offg = off + g*(NNODES+1);

  #pragma unroll
  for (int i=0;i<4;i++){
    const int d = dgrp*16 + w*4 + i;
    const int j0 = offg[d], j1 = offg[d+1];
    float a0=0.f, a1=0.f, a2=0.f, a3=0.f;
    int j = j0;
    for (; j+4 <= j1; j+=4){
      int s0=sp[j], s1=sp[j+1], s2=sp[j+2], s3=sp[j+3];
      ushort4 u0 = *(const ushort4*)&zb[(size_t)s0*256];
      ushort4 u1 = *(const ushort4*)&zb[(size_t)s1*256];
      ushort4 u2 = *(const ushort4*)&zb[(size_t)s2*256];
      ushort4 u3 = *(const ushort4*)&zb[(size_t)s3*256];
      a0 += bfdec(u0.x)+bfdec(u1.x)+bfdec(u2.x)+bfdec(u3.x);
      a1 += bfdec(u0.y)+bfdec(u1.y)+bfdec(u2.y)+bfdec(u3.y);
      a2 += bfdec(u0.z)+bfdec(u1.z)+bfdec(u2.z)+bfdec(u3.z);
      a3 += bfdec(u0.w)+bfdec(u1.w)+bfdec(u2.w)+bfdec(u3.w);
    }
    for (; j < j1; j++){
      ushort4 u = *(const ushort4*)&zb[(size_t)sp[j]*256];
      a0 += bfdec(u.x); a1 += bfdec(u.y); a2 += bfdec(u.z); a3 += bfdec(u.w);
    }
    size_t so = (size_t)(b*10000 + d)*512 + si*256 + lane*4;
    ushort4 h;
    h.x = f2bf_u(a0); h.y = f2bf_u(a1); h.z = f2bf_u(a2); h.w = f2bf_u(a3);
    *(ushort4*)&Sb[so] = h;
  }
}

// ---- ihcat.ib = S @ W2k^T (2-term K'=1024) + deg.b2: NCOL=2 ----
__global__ __launch_bounds__(256) void w264_kernel(
    const unsigned short* __restrict__ Sb, const unsigned short* __restrict__ w2k,
    const float* __restrict__ eb2, const int* __restrict__ off,
    unsigned short* __restrict__ ihcat)
{
  __shared__ unsigned short lds[12288];
  XDECODE(2)
  const int row0 = rb_*64, col0 = colb_*128;
  MMPRO
  mm64_core<1024,512,511>(Sb + (size_t)row0*512, w2k + (size_t)col0*1024, lds, acc);

  float b20[2], b21[2];
  #pragma unroll
  for (int ni=0;ni<2;ni++){
    int n = col0 + wc + ni*16 + col;
    b20[ni] = eb2[n];
    b21[ni] = eb2[256 + n];
  }
  #pragma unroll
  for (int mi=0;mi<4;mi++)
    #pragma unroll
    for (int rr=0;rr<4;rr++){
      int row = row0 + mi*16 + q*4 + rr;
      int b = row / 10000, d = row - b*10000;
      int o0 = (b*2)*(NNODES+1) + d;
      int o1 = (b*2+1)*(NNODES+1) + d;
      float dg0 = (float)(off[o0+1] - off[o0]);
      float dg1 = (float)(off[o1+1] - off[o1]);
      #pragma unroll
      for (int ni=0;ni<2;ni++){
        int n = col0 + wc + ni*16 + col;
        ihcat[(size_t)row*512 + n] = f2bf_u(acc[mi][ni][rr] + dg0*b20[ni] + dg1*b21[ni]);
      }
    }
}

// ---- gruA: combined r,z GEMM -> u16 gates. NCOL=4 ----
__global__ __launch_bounds__(256) void gruA_kernel(
    const unsigned short* __restrict__ ihcat, const unsigned short* __restrict__ wcomb,
    const float* __restrict__ b_ih, const float* __restrict__ b_hh,
    unsigned short* __restrict__ rz_r, unsigned short* __restrict__ rz_z)
{
  __shared__ unsigned short lds[12288];
  XDECODE(4)
  const int row0 = rb_*64, col0 = colb_*128;
  MMPRO
  mm64_core<1024,512,511>(ihcat + (size_t)row0*512, wcomb + (size_t)col0*1024, lds, acc);

  float bb[2];
  #pragma unroll
  for (int ni=0;ni<2;ni++){
    int n = col0 + wc + ni*16 + col;
    bb[ni] = b_ih[n] + b_hh[n];
  }
  unsigned short* dst = (col0 < 256) ? rz_r : rz_z;
  const int cbase = (col0 & 255) + wc;
  #pragma unroll
  for (int mi=0;mi<4;mi++)
    #pragma unroll
    for (int rr=0;rr<4;rr++){
      size_t row = (size_t)(row0 + mi*16 + q*4 + rr);
      #pragma unroll
      for (int ni=0;ni<2;ni++){
        float v = fsig(acc[mi][ni][rr] + bb[ni]);
        dst[row*256 + cbase + ni*16 + col] = (unsigned short)(v*GATE_SCL + 0.5f);
      }
    }
}

// ---- gruB: n gate + GRU update. NCOL=2. Writes ihcat_nxt h-half + h_lo ----
__global__ __launch_bounds__(256) void gruB_kernel(
    const unsigned short* __restrict__ ihcat, unsigned short* __restrict__ h_lo,
    const unsigned short* __restrict__ wihk, const unsigned short* __restrict__ whhk,
    const float* __restrict__ b_ih, const float* __restrict__ b_hh,
    const unsigned short* __restrict__ rz_r, const unsigned short* __restrict__ rz_z,
    unsigned short* __restrict__ ihcat_nxt)
{
  __shared__ unsigned short lds[12288];
  XDECODE(2)
  const int row0 = rb_*64, dcol0 = colb_*128;   // n-gate W cols = 512 + dcol0
  const int t = threadIdx.x, w = t >> 6, lane = t & 63;
  const int q = lane >> 4, col = lane & 15;
  const int wc = w*32;

  floatx4 ai[4][2], ah[4][2];
  #pragma unroll
  for (int mi=0;mi<4;mi++)
    #pragma unroll
    for (int ni=0;ni<2;ni++){ ai[mi][ni] = (floatx4){0.f,0.f,0.f,0.f}; ah[mi][ni] = (floatx4){0.f,0.f,0.f,0.f}; }

  mm64_core<512,512,255>(ihcat + (size_t)row0*512,       wihk + (size_t)(512 + dcol0)*512, lds, ai);
  mm64_core<512,512,255>(ihcat + (size_t)row0*512 + 256, whhk + (size_t)(512 + dcol0)*512, lds, ah);

  float bi[2], bh[2];
  #pragma unroll
  for (int ni=0;ni<2;ni++){
    int n = 512 + dcol0 + wc + ni*16 + col;
    bi[ni] = b_ih[n]; bh[ni] = b_hh[n];
  }
  #pragma unroll
  for (int mi=0;mi<4;mi++)
    #pragma unroll
    for (int rr=0;rr<4;rr++){
      size_t row = (size_t)(row0 + mi*16 + q*4 + rr);
      #pragma unroll
      for (int ni=0;ni<2;ni++){
        int dn = dcol0 + wc + ni*16 + col;
        float rg = (float)rz_r[row*256 + dn] * GATE_INV;
        float zg = (float)rz_z[row*256 + dn] * GATE_INV;
        float ng = ftanh(ai[mi][ni][rr] + bi[ni] + rg*(ah[mi][ni][rr] + bh[ni]));
        float hv = bfdec(ihcat[row*512 + 256 + dn]) + bfdec(h_lo[row*256 + dn]);
        float hnew = (1.f - zg)*ng + zg*hv;
        unsigned short hh = f2bf_u(hnew);
        ihcat_nxt[row*512 + 256 + dn] = hh;
        h_lo[row*256 + dn] = f2bf_u(hnew - bfdec(hh));
      }
    }
}

__global__ void reduce_kernel(const unsigned short* __restrict__ ihcat,
                              const unsigned short* __restrict__ h_lo,
                              float* __restrict__ sbuf){
  int b  = blockIdx.x / 50;
  int s0 = (blockIdx.x % 50) * 200;
  int d  = threadIdx.x;
  size_t row = (size_t)b*NNODES + s0;
  float acc = 0.f;
  for (int i=0;i<200;i++){
    acc += bfdec(ihcat[(row+i)*512 + 256 + d]) + bfdec(h_lo[(row+i)*256 + d]);
  }
  atomicAdd(&sbuf[b*DIM + d], acc);
}

__global__ __launch_bounds__(320) void head_kernel(
    const float* __restrict__ sbuf, const float* __restrict__ pt,
    const float* __restrict__ fc1w, const float* __restrict__ fc1b,
    const float* __restrict__ fc2w, const float* __restrict__ fc2b,
    const float* __restrict__ fc3w, const float* __restrict__ fc3b,
    float* __restrict__ out)
{
  __shared__ float L[4][257];
  __shared__ float T1[4][80];
  __shared__ float T2[4][80];
  __shared__ float fmx[4];
  int t = threadIdx.x;
  if (t < 256){
    for (int b=0;b<4;b++){
      float v = sbuf[b*DIM + t];
      float ll = logf(v);
      if (ll != ll) ll = 0.f;
      ll = fmaxf(ll, 0.f);
      L[b][t] = ll;
    }
  }
  __syncthreads();
  int w = t >> 6, lane = t & 63;
  if (w < 4){
    float m = -INFINITY;
    for (int i=lane;i<256;i+=64){ float v = L[w][i]; if (v != INFINITY) m = fmaxf(m, v); }
    #pragma unroll
    for (int o=32;o>=1;o>>=1) m = fmaxf(m, __shfl_xor(m, o, 64));
    if (lane==0) fmx[w] = m;
  }
  __syncthreads();
  if (t < 256){
    for (int b=0;b<4;b++) if (L[b][t] == INFINITY) L[b][t] = fmx[b];
  }
  if (t < 4) L[t][256] = pt[t];
  __syncthreads();
  if (t < 320){
    int b = t/80, i = t%80;
    float a = fc1b[i];
    for (int k=0;k<257;k++) a += L[b][k]*fc1w[i*257+k];
    T1[b][i] = leakyf(a);
  }
  __syncthreads();
  if (t < 320){
    int b = t/80, i = t%80;
    float a = fc2b[i];
    for (int k=0;k<80;k++) a += T1[b][k]*fc2w[i*80+k];
    T2[b][i] = leakyf(a);
  }
  __syncthreads();
  if (t < 40){
    int b = t/10, i = t%10;
    float a = fc3b[i];
    for (int k=0;k<80;k++) a += T2[b][k]*fc3w[i*80+k];
    out[b*10+i] = a;
  }
}

extern "C" void kernel_launch(void* const* d_in, const int* in_sizes, int n_in,
                              void* d_out, int out_size, void* d_ws, size_t ws_size,
                              hipStream_t stream) {
  const float* nodes = (const float*)d_in[0];
  const int*   edges = (const int*)d_in[1];
  const float* pt    = (const float*)d_in[2];
  const float* w_ih  = (const float*)d_in[3];
  const float* w_hh  = (const float*)d_in[4];
  const float* b_ih  = (const float*)d_in[5];
  const float* b_hh  = (const float*)d_in[6];
  const float* ew1   = (const float*)d_in[7];
  const float* eb1   = (const float*)d_in[8];
  const float* ew2   = (const float*)d_in[9];
  const float* eb2   = (const float*)d_in[10];
  const float* fc1w  = (const float*)d_in[11];
  const float* fc1b  = (const float*)d_in[12];
  const float* fc2w  = (const float*)d_in[13];
  const float* fc2b  = (const float*)d_in[14];
  const float* fc3w  = (const float*)d_in[15];
  const float* fc3b  = (const float*)d_in[16];

  const size_t HN  = (size_t)BATCH*NNODES*DIM;    // 10,240,000 (real rows)
  const size_t HNP = (size_t)MROWS*DIM;
  char* p = (char*)d_ws;
  float* sbuf = (float*)p;                        p += BATCH*DIM*4;
  unsigned short* ihcat0 = (unsigned short*)p;    p += (size_t)MROWS*512*2;  // [ib | h]
  unsigned short* ihcat1 = (unsigned short*)p;    p += (size_t)MROWS*512*2;
  unsigned short* h_lo   = (unsigned short*)p;    p += HNP*2;
  unsigned short* Zb   = (unsigned short*)p;      p += 2*HNP*2;              // z/agg scratch
  unsigned short* Sb   = (unsigned short*)p;      p += (size_t)MROWS*512*2;  // dead after w2 -> rz
  unsigned short* w1cat= (unsigned short*)p;      p += 512*256*2;
  unsigned short* w2k  = (unsigned short*)p;      p += 256*1024*2;
  unsigned short* wihk = (unsigned short*)p;      p += 768*512*2;
  unsigned short* whhk = (unsigned short*)p;      p += 768*512*2;
  unsigned short* wcomb= (unsigned short*)p;      p += 512*1024*2;
  int* off  = (int*)p;                            p += NG*(NNODES+1)*4;
  int* cur  = (int*)p;                            p += NG*NNODES*4;
  int* ssrc = (int*)p;                            p += (size_t)NG*NEDGES*4;

  unsigned short* rz_r = (unsigned short*)Sb;              // MROWS*256 u16
  unsigned short* rz_z = rz_r + (size_t)MROWS*256;         // MROWS*256 u16

  // weights
  w1cat_kernel<<<512,256,0,stream>>>(ew1, w1cat);
  w2k_kernel<<<1024,256,0,stream>>>(ew2, w2k);
  wk2_kernel<<<1536,256,0,stream>>>(w_ih, wihk);
  wk2_kernel<<<1536,256,0,stream>>>(w_hh, whhk);
  wcomb_kernel<<<2048,256,0,stream>>>(w_ih, w_hh, wcomb);

  // h0
  ihinit_kernel<<<(int)(HN/256),256,0,stream>>>(nodes, ihcat0, h_lo);

  // counting sort (CSR) of edges by dst, per stream g
  hipMemsetAsync(cur, 0, NG*NNODES*sizeof(int), stream);
  hist_kernel<<<(NG*NEDGES)/256,256,0,stream>>>(edges, cur);
  scan_kernel<<<NG,256,0,stream>>>(cur, off);
  hipMemsetAsync(cur, 0, NG*NNODES*sizeof(int), stream);
  scatter_kernel<<<(NG*NEDGES)/256,256,0,stream>>>(edges, off, cur, ssrc);

  hipMemsetAsync(sbuf, 0, BATCH*DIM*sizeof(float), stream);

  unsigned short* ih[2] = {ihcat0, ihcat1};

  for (int pass=0; pass<6; pass++){
    unsigned short* curb = ih[pass & 1];
    unsigned short* nxtb = ih[(pass+1) & 1];
    z64_kernel<<<RGRP*8*4,256,0,stream>>>(curb, w1cat, eb1, Zb);
    aggregate_kernel<<<5000,256,0,stream>>>(Zb, ssrc, off, Sb);
    w264_kernel<<<RGRP*8*2,256,0,stream>>>(Sb, w2k, eb2, off, curb);
    gruA_kernel<<<RGRP*8*4,256,0,stream>>>(curb, wcomb, b_ih, b_hh, rz_r, rz_z);
    gruB_kernel<<<RGRP*8*2,256,0,stream>>>(curb, h_lo, wihk, whhk, b_ih, b_hh,
                                           rz_r, rz_z, nxtb);
  }
  reduce_kernel<<<200,256,0,stream>>>(ih[0], h_lo, sbuf);
  head_kernel<<<1,320,0,stream>>>(sbuf, pt, fc1w,fc1b,fc2w,fc2b,fc3w,fc3b,(float*)d_out);
}